// Round 4
// baseline (540.766 us; speedup 1.0000x reference)
//
#include <hip/hip_runtime.h>
#include <cstdint>
#include <cstddef>

typedef unsigned short u16;
typedef unsigned long long u64;
typedef __attribute__((ext_vector_type(8))) short short8;
typedef __attribute__((ext_vector_type(4))) float f32x4;

#define T_SEQ 2048
#define DM    2048
#define NHEAD 16
#define NKV   4
#define HD    128
#define NEGBIG (-3.0e38f)
// 1/sqrt(128) * log2(e): softmax runs in exp2 domain
#define QSCALE 0.1275525165017459f

__device__ __forceinline__ u16 f2bf(float f) {
  union { float f; unsigned u; } c; c.f = f;
  return (u16)((c.u + 0x7fffu + ((c.u >> 16) & 1u)) >> 16);
}
__device__ __forceinline__ float bf2f(u16 b) {
  union { float f; unsigned u; } c; c.u = ((unsigned)b) << 16;
  return c.f;
}
__device__ __forceinline__ void gl_lds16(const u16* g, u16* l) {
  __builtin_amdgcn_global_load_lds(
      (const __attribute__((address_space(1))) void*)g,
      (__attribute__((address_space(3))) void*)l, 16, 0, 0);
}

// ---------------- fused cast fp32 -> bf16 (all 5 tensors, dst contiguous) ---
__global__ void castk_all(const float* __restrict__ x, const float* __restrict__ wq,
                          const float* __restrict__ wk, const float* __restrict__ wv,
                          const float* __restrict__ wo, u16* __restrict__ dst) {
  long long i4 = (long long)blockIdx.x * 256 + threadIdx.x;  // unit = 4 elems
  const float* src; long long off;
  if (i4 < (2LL << 20))                    { src = x;  off = i4; }
  else if (i4 < (3LL << 20))               { src = wq; off = i4 - (2LL << 20); }
  else if (i4 < (3LL << 20) + (1 << 18))   { src = wk; off = i4 - (3LL << 20); }
  else if (i4 < (3LL << 20) + (2 << 18))   { src = wv; off = i4 - (3LL << 20) - (1 << 18); }
  else                                     { src = wo; off = i4 - (3LL << 20) - (2 << 18); }
  float4 v = *(const float4*)(src + off * 4);
  u16* d = dst + i4 * 4;
  d[0] = f2bf(v.x); d[1] = f2bf(v.y); d[2] = f2bf(v.z); d[3] = f2bf(v.w);
}

// ---------------- fused RoPE in-place on Q and K ([rows, HD] bf16) ----------
__global__ void ropek_all(u16* __restrict__ Qb, u16* __restrict__ Kb) {
  int idx = blockIdx.x * 256 + threadIdx.x;
  int r = idx >> 6, i = idx & 63;
  u16* buf; int rr;
  if (r < 2 * NHEAD * T_SEQ) { buf = Qb; rr = r; }
  else                       { buf = Kb; rr = r - 2 * NHEAD * T_SEQ; }
  int t = rr & (T_SEQ - 1);
  float inv = expf(-0.215867352496f * (float)i);  // 1e6^(-i/64)
  float ang = (float)t * inv;
  float c = cosf(ang), s = sinf(ang);
  size_t base = (size_t)rr * HD + i;
  float x1 = bf2f(buf[base]), x2 = bf2f(buf[base + 64]);
  buf[base]      = f2bf(x1 * c - x2 * s);
  buf[base + 64] = f2bf(x2 * c + x1 * s);
}

// ---------------- GEMM: C[M,N] = A[M,K] @ Bm[N,K]^T  (bf16 in, MFMA) -------
// MODE 0: fp32 plain row-major out (Out0)
// MODE 3: fused QKV epilogue: n<2048 -> Q [B,NH,T,HD] *QSCALE;
//         n<2560 -> K [B,NKV,T,HD]; else V^T [B,NKV,HD,T]
template <int MODE>
__global__ __launch_bounds__(256) void gemm_bt(
    const u16* __restrict__ A, const u16* __restrict__ Bm,
    void* __restrict__ Out0, u16* __restrict__ OutK, u16* __restrict__ OutV,
    int M, int N, int K) {
  __shared__ __align__(16) u16 As[128 * 32];
  __shared__ __align__(16) u16 Bs[128 * 32];
  const int tid = threadIdx.x;
  const int w = tid >> 6, l = tid & 63;
  const int lm = l & 15, q = l >> 4;
  const int m0 = blockIdx.y * 128, n0 = blockIdx.x * 128;
  const int mq = w & 1, nq = w >> 1;
  const u16* Ab = A + (size_t)m0 * K;
  const u16* Bb = Bm + (size_t)n0 * K;

  f32x4 acc[4][4] = {};

  for (int k0 = 0; k0 < K; k0 += 32) {
#pragma unroll
    for (int c = 0; c < 2; ++c) {
      int s = c * 256 + w * 64 + l;  // 16B slot id; row = s>>2, kq = s&3
      int row = s >> 2, kq = s & 3;
      gl_lds16(Ab + (size_t)row * K + k0 + kq * 8, As + s * 8);
      gl_lds16(Bb + (size_t)row * K + k0 + kq * 8, Bs + s * 8);
    }
    __syncthreads();
    short8 af[4], bf[4];
#pragma unroll
    for (int i = 0; i < 4; ++i) {
      af[i] = *(const short8*)(As + (mq * 64 + i * 16 + lm) * 32 + q * 8);
      bf[i] = *(const short8*)(Bs + (nq * 64 + i * 16 + lm) * 32 + q * 8);
    }
#pragma unroll
    for (int i = 0; i < 4; ++i)
#pragma unroll
      for (int j = 0; j < 4; ++j)
        acc[i][j] = __builtin_amdgcn_mfma_f32_16x16x32_bf16(af[i], bf[j], acc[i][j], 0, 0, 0);
    __syncthreads();
  }

#pragma unroll
  for (int i = 0; i < 4; ++i)
#pragma unroll
    for (int j = 0; j < 4; ++j)
#pragma unroll
      for (int r = 0; r < 4; ++r) {
        int m = m0 + mq * 64 + i * 16 + q * 4 + r;
        int n = n0 + nq * 64 + j * 16 + lm;
        float v = acc[i][j][r];
        if constexpr (MODE == 0) {
          ((float*)Out0)[(size_t)m * N + n] = v;
        } else {
          int b = m >> 11, t = m & (T_SEQ - 1);
          if (n < 2048) {
            int h = n >> 7, d = n & (HD - 1);
            ((u16*)Out0)[(((size_t)(b * NHEAD + h)) * T_SEQ + t) * HD + d] = f2bf(v * QSCALE);
          } else if (n < 2560) {
            int nn = n - 2048, h = nn >> 7, d = nn & (HD - 1);
            OutK[(((size_t)(b * NKV + h)) * T_SEQ + t) * HD + d] = f2bf(v);
          } else {
            int nn = n - 2560, h = nn >> 7, d = nn & (HD - 1);
            OutV[(((size_t)(b * NKV + h)) * HD + d) * T_SEQ + t] = f2bf(v);
          }
        }
      }
}

// ---------------- flash attention v3 ----------------
// S^T: mfma(kb, qa) -> C[s][qrow].  O^T: mfma(vb, pa) -> C[d][qrow] so that
// alpha/l_i (per qrow = lane) rescale O with NO cross-lane ops. Softmax:
// 16 in-register values + 2 shfl_xor. No __syncthreads anywhere.
// 512 blocks (2/CU), 4 waves x 16 qrows = 64-row tiles; pair {31-p, p}
// -> uniform 33 steps/block. Mask only the diagonal step.
// Q:[B,NH,T,HD] (pre-scaled QSCALE)  K:[B,NKV,T,HD]  V:[B,NKV,HD,T]
#define PSTRIDE 72
__global__ __launch_bounds__(256, 2) void attnk(
    const u16* __restrict__ Q, const u16* __restrict__ Kh,
    const u16* __restrict__ Vt, u16* __restrict__ Oa) {
  __shared__ __align__(16) u16 Pl[4][16 * PSTRIDE];
  const int tid = threadIdx.x;
  const int w = tid >> 6, l = tid & 63, lm = l & 15, q = l >> 4;
  const int bh = blockIdx.y, b = bh >> 4, h = bh & 15, kvh = h >> 2;
  const u16* Kb = Kh + ((size_t)(b * NKV + kvh)) * T_SEQ * HD;
  const u16* Vb = Vt + ((size_t)(b * NKV + kvh)) * HD * T_SEQ;
  u16* Pw = Pl[w];
  const int p = blockIdx.x;  // 0..15

#pragma unroll 1
  for (int half = 0; half < 2; ++half) {
    const int tile = half ? p : (31 - p);  // heavy tile first
    const int tbase = tile * 64 + w * 16;
    const u16* Qb = Q + (((size_t)(b * NHEAD + h)) * T_SEQ + tbase) * HD;

    short8 qa[4];
#pragma unroll
    for (int ks = 0; ks < 4; ++ks)
      qa[ks] = *(const short8*)(Qb + (size_t)lm * HD + ks * 32 + q * 8);

    float m_i = NEGBIG, l_i = 0.f;
    f32x4 oacc[8] = {};
    const int nst = tile + 1;

    for (int st = 0; st < nst; ++st) {
      const int s0 = st * 64;
      f32x4 sacc[4] = {};
#pragma unroll
      for (int ks = 0; ks < 4; ++ks)
#pragma unroll
        for (int nt = 0; nt < 4; ++nt) {
          short8 kb = *(const short8*)(Kb + (size_t)(s0 + nt * 16 + lm) * HD + ks * 32 + q * 8);
          sacc[nt] = __builtin_amdgcn_mfma_f32_16x16x32_bf16(kb, qa[ks], sacc[nt], 0, 0, 0);
        }

      const bool diag = (st == nst - 1);
      float mx = m_i;
      float pe[4][4];
#pragma unroll
      for (int nt = 0; nt < 4; ++nt)
#pragma unroll
        for (int j = 0; j < 4; ++j) {
          float v = sacc[nt][j];
          if (diag) {
            int s_abs = s0 + nt * 16 + q * 4 + j;
            if (s_abs > tbase + lm) v = NEGBIG;
          }
          pe[nt][j] = v;
          mx = fmaxf(mx, v);
        }
      mx = fmaxf(mx, __shfl_xor(mx, 16, 64));
      mx = fmaxf(mx, __shfl_xor(mx, 32, 64));
      float alpha = exp2f(m_i - mx);
      float sum = 0.f;
#pragma unroll
      for (int nt = 0; nt < 4; ++nt) {
        u16 pk[4];
#pragma unroll
        for (int j = 0; j < 4; ++j) {
          float e = exp2f(pe[nt][j] - mx);
          sum += e;
          pk[j] = f2bf(e);
        }
        *(u64*)(Pw + lm * PSTRIDE + nt * 16 + q * 4) =
            (u64)pk[0] | ((u64)pk[1] << 16) | ((u64)pk[2] << 32) | ((u64)pk[3] << 48);
      }
      sum += __shfl_xor(sum, 16, 64);
      sum += __shfl_xor(sum, 32, 64);
      m_i = mx;
      l_i = l_i * alpha + sum;

      // rescale O^T by alpha: per-lane (col = qrow = lm) — no cross-lane ops
#pragma unroll
      for (int dt = 0; dt < 8; ++dt)
#pragma unroll
        for (int j = 0; j < 4; ++j) oacc[dt][j] *= alpha;

      // pin compile-time order: P LDS-writes precede PV LDS-reads
      asm volatile("" ::: "memory");

      // PV: O^T += V^T · P~  (vb is A-operand, pa is B-operand)
#pragma unroll
      for (int ks = 0; ks < 2; ++ks) {
        short8 pa = *(const short8*)(Pw + lm * PSTRIDE + ks * 32 + q * 8);
#pragma unroll
        for (int dt = 0; dt < 8; ++dt) {
          short8 vb = *(const short8*)(Vb + (size_t)(dt * 16 + lm) * T_SEQ + s0 + ks * 32 + q * 8);
          oacc[dt] = __builtin_amdgcn_mfma_f32_16x16x32_bf16(vb, pa, oacc[dt], 0, 0, 0);
        }
      }
    }

    // epilogue: O^T[d][qrow]: row d = dt*16 + q*4 + j, col qrow = lm (per-lane l_i)
    float inv = 1.0f / l_i;
    int t = tbase + lm;
#pragma unroll
    for (int dt = 0; dt < 8; ++dt) {
      u16 ok[4];
#pragma unroll
      for (int j = 0; j < 4; ++j) ok[j] = f2bf(oacc[dt][j] * inv);
      *(u64*)(Oa + ((size_t)(b * T_SEQ + t)) * (NHEAD * HD) + h * HD + dt * 16 + q * 4) =
          (u64)ok[0] | ((u64)ok[1] << 16) | ((u64)ok[2] << 32) | ((u64)ok[3] << 48);
    }
  }
}

extern "C" void kernel_launch(void* const* d_in, const int* in_sizes, int n_in,
                              void* d_out, int out_size, void* d_ws, size_t ws_size,
                              hipStream_t stream) {
  const float* x  = (const float*)d_in[0];
  const float* wq = (const float*)d_in[1];
  const float* wk = (const float*)d_in[2];
  const float* wv = (const float*)d_in[3];
  const float* wo = (const float*)d_in[4];
  float* out = (float*)d_out;

  u16* ws  = (u16*)d_ws;
  u16* xb  = ws;                      // 8M elems  (x bf16)  [later: attn out]
  u16* wqb = xb  + (8u << 20);        // 4M   } contiguous
  u16* wkb = wqb + (4u << 20);        // 1M   }  -> fused QKV weight [3072,2048]
  u16* wvb = wkb + (1u << 20);        // 1M   }
  u16* wob = wvb + (1u << 20);        // 4M
  u16* Qb  = wob + (4u << 20);        // 8M
  u16* Kb  = Qb  + (8u << 20);        // 2M
  u16* Vtb = Kb  + (2u << 20);        // 2M
  u16* Ab  = xb;                      // alias: 8M  (total 30M elems = 60 MB)

  // 1. fused cast (dst = ws[0 .. 18M) contiguous in exactly this order)
  castk_all<<<18432, 256, 0, stream>>>(x, wq, wk, wv, wo, ws);

  // 2. fused QKV projection: [4096,2048] @ [3072,2048]^T, 768 blocks = 3/CU
  gemm_bt<3><<<dim3(24, 32), 256, 0, stream>>>(xb, wqb, Qb, Kb, Vtb, 4096, 3072, 2048);

  // 3. fused RoPE on Q (65536 rows) and K (16384 rows)
  ropek_all<<<20480, 256, 0, stream>>>(Qb, Kb);

  // 4. attention: grid (16 tile-pairs, B*NHEAD = 32) = 512 blocks, 2/CU
  attnk<<<dim3(16, 32), 256, 0, stream>>>(Qb, Kb, Vtb, Ab);

  // 5. output projection -> fp32 d_out
  gemm_bt<0><<<dim3(16, 32), 256, 0, stream>>>(Ab, wob, out, nullptr, nullptr, 4096, 2048, 2048);
}

// Round 5
// 328.602 us; speedup vs baseline: 1.6457x; 1.6457x over previous
//
#include <hip/hip_runtime.h>
#include <cstdint>
#include <cstddef>

typedef unsigned short u16;
typedef unsigned long long u64;
typedef __attribute__((ext_vector_type(8))) short short8;
typedef __attribute__((ext_vector_type(4))) float f32x4;

#define T_SEQ 2048
#define DM    2048
#define NHEAD 16
#define NKV   4
#define HD    128
#define NEGBIG (-3.0e38f)
// 1/sqrt(128) * log2(e): softmax runs in exp2 domain
#define QSCALE 0.1275525165017459f

__device__ __forceinline__ u16 f2bf(float f) {
  union { float f; unsigned u; } c; c.f = f;
  return (u16)((c.u + 0x7fffu + ((c.u >> 16) & 1u)) >> 16);
}
__device__ __forceinline__ float bf2f(u16 b) {
  union { float f; unsigned u; } c; c.u = ((unsigned)b) << 16;
  return c.f;
}
__device__ __forceinline__ void gl_lds16(const u16* g, u16* l) {
  __builtin_amdgcn_global_load_lds(
      (const __attribute__((address_space(1))) void*)g,
      (__attribute__((address_space(3))) void*)l, 16, 0, 0);
}

// ---------------- fused cast fp32 -> bf16 (all 5 tensors, dst contiguous) ---
__global__ void castk_all(const float* __restrict__ x, const float* __restrict__ wq,
                          const float* __restrict__ wk, const float* __restrict__ wv,
                          const float* __restrict__ wo, u16* __restrict__ dst) {
  long long i4 = (long long)blockIdx.x * 256 + threadIdx.x;  // unit = 4 elems
  const float* src; long long off;
  if (i4 < (2LL << 20))                    { src = x;  off = i4; }
  else if (i4 < (3LL << 20))               { src = wq; off = i4 - (2LL << 20); }
  else if (i4 < (3LL << 20) + (1 << 18))   { src = wk; off = i4 - (3LL << 20); }
  else if (i4 < (3LL << 20) + (2 << 18))   { src = wv; off = i4 - (3LL << 20) - (1 << 18); }
  else                                     { src = wo; off = i4 - (3LL << 20) - (2 << 18); }
  float4 v = *(const float4*)(src + off * 4);
  u16* d = dst + i4 * 4;
  d[0] = f2bf(v.x); d[1] = f2bf(v.y); d[2] = f2bf(v.z); d[3] = f2bf(v.w);
}

// ---------------- fused RoPE in-place on Q and K ([rows, HD] bf16) ----------
__global__ void ropek_all(u16* __restrict__ Qb, u16* __restrict__ Kb) {
  int idx = blockIdx.x * 256 + threadIdx.x;
  int r = idx >> 6, i = idx & 63;
  u16* buf; int rr;
  if (r < 2 * NHEAD * T_SEQ) { buf = Qb; rr = r; }
  else                       { buf = Kb; rr = r - 2 * NHEAD * T_SEQ; }
  int t = rr & (T_SEQ - 1);
  float inv = expf(-0.215867352496f * (float)i);  // 1e6^(-i/64)
  float ang = (float)t * inv;
  float c = cosf(ang), s = sinf(ang);
  size_t base = (size_t)rr * HD + i;
  float x1 = bf2f(buf[base]), x2 = bf2f(buf[base + 64]);
  buf[base]      = f2bf(x1 * c - x2 * s);
  buf[base + 64] = f2bf(x2 * c + x1 * s);
}

// ---------------- GEMM: C[M,N] = A[M,K] @ Bm[N,K]^T  (bf16 in, MFMA) -------
// MODE 0: fp32 plain row-major out (Out0)
// MODE 3: fused QKV epilogue: n<2048 -> Q [B,NH,T,HD] *QSCALE;
//         n<2560 -> K [B,NKV,T,HD]; else V^T [B,NKV,HD,T]
template <int MODE>
__global__ __launch_bounds__(256) void gemm_bt(
    const u16* __restrict__ A, const u16* __restrict__ Bm,
    void* __restrict__ Out0, u16* __restrict__ OutK, u16* __restrict__ OutV,
    int M, int N, int K) {
  __shared__ __align__(16) u16 As[128 * 32];
  __shared__ __align__(16) u16 Bs[128 * 32];
  const int tid = threadIdx.x;
  const int w = tid >> 6, l = tid & 63;
  const int lm = l & 15, q = l >> 4;
  const int m0 = blockIdx.y * 128, n0 = blockIdx.x * 128;
  const int mq = w & 1, nq = w >> 1;
  const u16* Ab = A + (size_t)m0 * K;
  const u16* Bb = Bm + (size_t)n0 * K;

  f32x4 acc[4][4] = {};

  for (int k0 = 0; k0 < K; k0 += 32) {
#pragma unroll
    for (int c = 0; c < 2; ++c) {
      int s = c * 256 + w * 64 + l;  // 16B slot id; row = s>>2, kq = s&3
      int row = s >> 2, kq = s & 3;
      gl_lds16(Ab + (size_t)row * K + k0 + kq * 8, As + s * 8);
      gl_lds16(Bb + (size_t)row * K + k0 + kq * 8, Bs + s * 8);
    }
    __syncthreads();
    short8 af[4], bf[4];
#pragma unroll
    for (int i = 0; i < 4; ++i) {
      af[i] = *(const short8*)(As + (mq * 64 + i * 16 + lm) * 32 + q * 8);
      bf[i] = *(const short8*)(Bs + (nq * 64 + i * 16 + lm) * 32 + q * 8);
    }
#pragma unroll
    for (int i = 0; i < 4; ++i)
#pragma unroll
      for (int j = 0; j < 4; ++j)
        acc[i][j] = __builtin_amdgcn_mfma_f32_16x16x32_bf16(af[i], bf[j], acc[i][j], 0, 0, 0);
    __syncthreads();
  }

#pragma unroll
  for (int i = 0; i < 4; ++i)
#pragma unroll
    for (int j = 0; j < 4; ++j)
#pragma unroll
      for (int r = 0; r < 4; ++r) {
        int m = m0 + mq * 64 + i * 16 + q * 4 + r;
        int n = n0 + nq * 64 + j * 16 + lm;
        float v = acc[i][j][r];
        if constexpr (MODE == 0) {
          ((float*)Out0)[(size_t)m * N + n] = v;
        } else {
          int b = m >> 11, t = m & (T_SEQ - 1);
          if (n < 2048) {
            int h = n >> 7, d = n & (HD - 1);
            ((u16*)Out0)[(((size_t)(b * NHEAD + h)) * T_SEQ + t) * HD + d] = f2bf(v * QSCALE);
          } else if (n < 2560) {
            int nn = n - 2048, h = nn >> 7, d = nn & (HD - 1);
            OutK[(((size_t)(b * NKV + h)) * T_SEQ + t) * HD + d] = f2bf(v);
          } else {
            int nn = n - 2560, h = nn >> 7, d = nn & (HD - 1);
            OutV[(((size_t)(b * NKV + h)) * HD + d) * T_SEQ + t] = f2bf(v);
          }
        }
      }
}

// ---------------- flash attention v4: LDS-staged K/V ----------------
// S^T: mfma(kb, qa) -> C[s][qrow].  O^T: mfma(vb, pa) -> C[d][qrow]: alpha/l_i
// rescale is pure per-lane. K/V tiles staged to LDS by global_load_lds DMA,
// double-buffered, shared by all 4 waves (4x less VMEM, zero VGPR cost).
// Slot XOR-swizzle (K: ^s&15, V: ^d&7) spreads b128 reads evenly over banks.
// 512 blocks (2/CU); pair {31-p, p} -> uniform 33 steps. One barrier/step.
// Q:[B,NH,T,HD] (pre-scaled QSCALE)  K:[B,NKV,T,HD]  V:[B,NKV,HD,T]
#define PSTRIDE 72
__global__ __launch_bounds__(256, 2) void attnk(
    const u16* __restrict__ Q, const u16* __restrict__ Kh,
    const u16* __restrict__ Vt, u16* __restrict__ Oa) {
  __shared__ __align__(16) u16 Ks[2][64 * 128];   // [s][d], slot^ (s&15)
  __shared__ __align__(16) u16 Vs[2][128 * 64];   // [d][s], slot^ (d&7)
  __shared__ __align__(16) u16 Pl[4][16 * PSTRIDE];
  const int tid = threadIdx.x;
  const int w = tid >> 6, l = tid & 63, lm = l & 15, q = l >> 4;
  const int bh = blockIdx.y, b = bh >> 4, h = bh & 15, kvh = h >> 2;
  const u16* Kb = Kh + ((size_t)(b * NKV + kvh)) * T_SEQ * HD;
  const u16* Vb = Vt + ((size_t)(b * NKV + kvh)) * HD * T_SEQ;
  u16* Pw = Pl[w];
  const int p = blockIdx.x;  // 0..15

  // staging decomposition (per thread, 4+4 DMA instrs per tile)
  const int r16 = tid >> 4, c16 = tid & 15;  // K: row group, phys slot
  const int r8  = tid >> 3, c8  = tid & 7;   // V: row group, phys slot

#pragma unroll 1
  for (int half = 0; half < 2; ++half) {
    const int tile = half ? p : (31 - p);  // heavy tile first
    const int tbase = tile * 64 + w * 16;
    const u16* Qb = Q + (((size_t)(b * NHEAD + h)) * T_SEQ + tbase) * HD;

    short8 qa[4];
#pragma unroll
    for (int ks = 0; ks < 4; ++ks)
      qa[ks] = *(const short8*)(Qb + (size_t)lm * HD + ks * 32 + q * 8);

    float m_i = NEGBIG, l_i = 0.f;
    f32x4 oacc[8] = {};
    const int nst = tile + 1;

    // prologue: stage step 0 into buffer 0
    {
#pragma unroll
      for (int j = 0; j < 4; ++j) {
        int s = j * 16 + r16, g = c16 ^ (s & 15);
        gl_lds16(Kb + (size_t)s * HD + g * 8, &Ks[0][s * 128 + c16 * 8]);
      }
#pragma unroll
      for (int j = 0; j < 4; ++j) {
        int d = j * 32 + r8, g = c8 ^ (d & 7);
        gl_lds16(Vb + (size_t)d * T_SEQ + g * 8, &Vs[0][d * 64 + c8 * 8]);
      }
    }
    __syncthreads();

    for (int st = 0; st < nst; ++st) {
      const int bb = st & 1;
      // prefetch next tile into other buffer (overlaps with this step's compute)
      if (st + 1 < nst) {
        const int s0n = (st + 1) * 64;
#pragma unroll
        for (int j = 0; j < 4; ++j) {
          int s = j * 16 + r16, g = c16 ^ (s & 15);
          gl_lds16(Kb + (size_t)(s0n + s) * HD + g * 8, &Ks[bb ^ 1][s * 128 + c16 * 8]);
        }
#pragma unroll
        for (int j = 0; j < 4; ++j) {
          int d = j * 32 + r8, g = c8 ^ (d & 7);
          gl_lds16(Vb + (size_t)d * T_SEQ + s0n + g * 8, &Vs[bb ^ 1][d * 64 + c8 * 8]);
        }
      }

      // QK^T from LDS K-tile
      f32x4 sacc[4] = {};
#pragma unroll
      for (int ks = 0; ks < 4; ++ks)
#pragma unroll
        for (int nt = 0; nt < 4; ++nt) {
          short8 kb = *(const short8*)(&Ks[bb][(nt * 16 + lm) * 128 + ((ks * 4 + q) ^ lm) * 8]);
          sacc[nt] = __builtin_amdgcn_mfma_f32_16x16x32_bf16(kb, qa[ks], sacc[nt], 0, 0, 0);
        }

      const bool diag = (st == nst - 1);
      const int s0 = st * 64;
      float mx = m_i;
      float pe[4][4];
#pragma unroll
      for (int nt = 0; nt < 4; ++nt)
#pragma unroll
        for (int j = 0; j < 4; ++j) {
          float v = sacc[nt][j];
          if (diag) {
            int s_abs = s0 + nt * 16 + q * 4 + j;
            if (s_abs > tbase + lm) v = NEGBIG;
          }
          pe[nt][j] = v;
          mx = fmaxf(mx, v);
        }
      mx = fmaxf(mx, __shfl_xor(mx, 16, 64));
      mx = fmaxf(mx, __shfl_xor(mx, 32, 64));
      float alpha = exp2f(m_i - mx);
      float sum = 0.f;
#pragma unroll
      for (int nt = 0; nt < 4; ++nt) {
        u16 pk[4];
#pragma unroll
        for (int j = 0; j < 4; ++j) {
          float e = exp2f(pe[nt][j] - mx);
          sum += e;
          pk[j] = f2bf(e);
        }
        *(u64*)(Pw + lm * PSTRIDE + nt * 16 + q * 4) =
            (u64)pk[0] | ((u64)pk[1] << 16) | ((u64)pk[2] << 32) | ((u64)pk[3] << 48);
      }
      sum += __shfl_xor(sum, 16, 64);
      sum += __shfl_xor(sum, 32, 64);
      m_i = mx;
      l_i = l_i * alpha + sum;

      // rescale O^T by alpha: per-lane (col = qrow = lm) — no cross-lane ops
#pragma unroll
      for (int dt = 0; dt < 8; ++dt)
#pragma unroll
        for (int j = 0; j < 4; ++j) oacc[dt][j] *= alpha;

      // pin compile-time order: P LDS-writes precede PV LDS-reads
      asm volatile("" ::: "memory");

      // PV from LDS V-tile: O^T += V^T · P~
#pragma unroll
      for (int ks = 0; ks < 2; ++ks) {
        short8 pa = *(const short8*)(Pw + lm * PSTRIDE + ks * 32 + q * 8);
#pragma unroll
        for (int dt = 0; dt < 8; ++dt) {
          short8 vb = *(const short8*)(
              &Vs[bb][(dt * 16 + lm) * 64 + ((ks * 4 + q) ^ (lm & 7)) * 8]);
          oacc[dt] = __builtin_amdgcn_mfma_f32_16x16x32_bf16(vb, pa, oacc[dt], 0, 0, 0);
        }
      }
      __syncthreads();  // buffers swap-safe; also drains next-tile DMA
    }

    // epilogue: O^T[d][qrow]: row d = dt*16 + q*4 + j, col qrow = lm (per-lane l_i)
    float inv = 1.0f / l_i;
    int t = tbase + lm;
#pragma unroll
    for (int dt = 0; dt < 8; ++dt) {
      u16 ok[4];
#pragma unroll
      for (int j = 0; j < 4; ++j) ok[j] = f2bf(oacc[dt][j] * inv);
      *(u64*)(Oa + ((size_t)(b * T_SEQ + t)) * (NHEAD * HD) + h * HD + dt * 16 + q * 4) =
          (u64)ok[0] | ((u64)ok[1] << 16) | ((u64)ok[2] << 32) | ((u64)ok[3] << 48);
    }
  }
}

extern "C" void kernel_launch(void* const* d_in, const int* in_sizes, int n_in,
                              void* d_out, int out_size, void* d_ws, size_t ws_size,
                              hipStream_t stream) {
  const float* x  = (const float*)d_in[0];
  const float* wq = (const float*)d_in[1];
  const float* wk = (const float*)d_in[2];
  const float* wv = (const float*)d_in[3];
  const float* wo = (const float*)d_in[4];
  float* out = (float*)d_out;

  u16* ws  = (u16*)d_ws;
  u16* xb  = ws;                      // 8M elems  (x bf16)  [later: attn out]
  u16* wqb = xb  + (8u << 20);        // 4M   } contiguous
  u16* wkb = wqb + (4u << 20);        // 1M   }  -> fused QKV weight [3072,2048]
  u16* wvb = wkb + (1u << 20);        // 1M   }
  u16* wob = wvb + (1u << 20);        // 4M
  u16* Qb  = wob + (4u << 20);        // 8M
  u16* Kb  = Qb  + (8u << 20);        // 2M
  u16* Vtb = Kb  + (2u << 20);        // 2M
  u16* Ab  = xb;                      // alias: 8M  (total 30M elems = 60 MB)

  // 1. fused cast (dst = ws[0 .. 18M) contiguous in exactly this order)
  castk_all<<<18432, 256, 0, stream>>>(x, wq, wk, wv, wo, ws);

  // 2. fused QKV projection: [4096,2048] @ [3072,2048]^T, 768 blocks = 3/CU
  gemm_bt<3><<<dim3(24, 32), 256, 0, stream>>>(xb, wqb, Qb, Kb, Vtb, 4096, 3072, 2048);

  // 3. fused RoPE on Q (65536 rows) and K (16384 rows)
  ropek_all<<<20480, 256, 0, stream>>>(Qb, Kb);

  // 4. attention: grid (16 tile-pairs, B*NHEAD = 32) = 512 blocks, 2/CU
  attnk<<<dim3(16, 32), 256, 0, stream>>>(Qb, Kb, Vtb, Ab);

  // 5. output projection -> fp32 d_out
  gemm_bt<0><<<dim3(16, 32), 256, 0, stream>>>(Ab, wob, out, nullptr, nullptr, 4096, 2048, 2048);
}

// Round 6
// 307.027 us; speedup vs baseline: 1.7613x; 1.0703x over previous
//
#include <hip/hip_runtime.h>
#include <cstdint>
#include <cstddef>

typedef unsigned short u16;
typedef unsigned long long u64;
typedef __attribute__((ext_vector_type(8))) short short8;
typedef __attribute__((ext_vector_type(4))) float f32x4;

#define T_SEQ 2048
#define DM    2048
#define NHEAD 16
#define NKV   4
#define HD    128
#define NEGBIG (-3.0e38f)
// 1/sqrt(128) * log2(e): softmax runs in exp2 domain
#define QSCALE 0.1275525165017459f

__device__ __forceinline__ u16 f2bf(float f) {
  union { float f; unsigned u; } c; c.f = f;
  return (u16)((c.u + 0x7fffu + ((c.u >> 16) & 1u)) >> 16);
}
__device__ __forceinline__ float bf2f(u16 b) {
  union { float f; unsigned u; } c; c.u = ((unsigned)b) << 16;
  return c.f;
}
__device__ __forceinline__ void gl_lds16(const u16* g, u16* l) {
  __builtin_amdgcn_global_load_lds(
      (const __attribute__((address_space(1))) void*)g,
      (__attribute__((address_space(3))) void*)l, 16, 0, 0);
}

// ---------------- fused cast fp32 -> bf16 (all 5 tensors, dst contiguous) ---
__global__ void castk_all(const float* __restrict__ x, const float* __restrict__ wq,
                          const float* __restrict__ wk, const float* __restrict__ wv,
                          const float* __restrict__ wo, u16* __restrict__ dst) {
  long long i4 = (long long)blockIdx.x * 256 + threadIdx.x;  // unit = 4 elems
  const float* src; long long off;
  if (i4 < (2LL << 20))                    { src = x;  off = i4; }
  else if (i4 < (3LL << 20))               { src = wq; off = i4 - (2LL << 20); }
  else if (i4 < (3LL << 20) + (1 << 18))   { src = wk; off = i4 - (3LL << 20); }
  else if (i4 < (3LL << 20) + (2 << 18))   { src = wv; off = i4 - (3LL << 20) - (1 << 18); }
  else                                     { src = wo; off = i4 - (3LL << 20) - (2 << 18); }
  float4 v = *(const float4*)(src + off * 4);
  u16* d = dst + i4 * 4;
  d[0] = f2bf(v.x); d[1] = f2bf(v.y); d[2] = f2bf(v.z); d[3] = f2bf(v.w);
}

// ---------------- fused RoPE in-place on Q and K ([rows, HD] bf16) ----------
__global__ void ropek_all(u16* __restrict__ Qb, u16* __restrict__ Kb) {
  int idx = blockIdx.x * 256 + threadIdx.x;
  int r = idx >> 6, i = idx & 63;
  u16* buf; int rr;
  if (r < 2 * NHEAD * T_SEQ) { buf = Qb; rr = r; }
  else                       { buf = Kb; rr = r - 2 * NHEAD * T_SEQ; }
  int t = rr & (T_SEQ - 1);
  float inv = expf(-0.215867352496f * (float)i);  // 1e6^(-i/64)
  float ang = (float)t * inv;
  float c = cosf(ang), s = sinf(ang);
  size_t base = (size_t)rr * HD + i;
  float x1 = bf2f(buf[base]), x2 = bf2f(buf[base + 64]);
  buf[base]      = f2bf(x1 * c - x2 * s);
  buf[base + 64] = f2bf(x2 * c + x1 * s);
}

// ---------------- GEMM: C[M,N] = A[M,K] @ Bm[N,K]^T  (bf16 in, MFMA) -------
// K-loop: double-buffered LDS, prefetch DMA issued at top of iter, ONE
// barrier per iter (end-of-iter drain overlaps with this iter's compute).
// MODE 0: fp32 plain row-major out (Out0)
// MODE 3: fused QKV epilogue: n<2048 -> Q [B,NH,T,HD] *QSCALE;
//         n<2560 -> K [B,NKV,T,HD]; else V^T [B,NKV,HD,T]
template <int MODE>
__global__ __launch_bounds__(256) void gemm_bt(
    const u16* __restrict__ A, const u16* __restrict__ Bm,
    void* __restrict__ Out0, u16* __restrict__ OutK, u16* __restrict__ OutV,
    int M, int N, int K) {
  __shared__ __align__(16) u16 As[2][128 * 32];
  __shared__ __align__(16) u16 Bs[2][128 * 32];
  const int tid = threadIdx.x;
  const int w = tid >> 6, l = tid & 63;
  const int lm = l & 15, q = l >> 4;
  const int m0 = blockIdx.y * 128, n0 = blockIdx.x * 128;
  const int mq = w & 1, nq = w >> 1;
  const u16* Ab = A + (size_t)m0 * K;
  const u16* Bb = Bm + (size_t)n0 * K;

  // staging decomposition: slot s -> row = s>>2, k-quarter = s&3
  const int s0_ = w * 64 + l, s1_ = 256 + s0_;
  const int row0 = s0_ >> 2, kq0 = (s0_ & 3) * 8;
  const int row1 = s1_ >> 2, kq1 = (s1_ & 3) * 8;

  f32x4 acc[4][4] = {};
  const int nk = K >> 5;

  // prologue: stage k-tile 0 into buffer 0
  gl_lds16(Ab + (size_t)row0 * K + kq0, &As[0][s0_ * 8]);
  gl_lds16(Bb + (size_t)row0 * K + kq0, &Bs[0][s0_ * 8]);
  gl_lds16(Ab + (size_t)row1 * K + kq1, &As[0][s1_ * 8]);
  gl_lds16(Bb + (size_t)row1 * K + kq1, &Bs[0][s1_ * 8]);
  __syncthreads();

  for (int ki = 0; ki < nk; ++ki) {
    const int bb = ki & 1;
    if (ki + 1 < nk) {  // prefetch next k-tile into other buffer
      const int k0 = (ki + 1) << 5;
      gl_lds16(Ab + (size_t)row0 * K + k0 + kq0, &As[bb ^ 1][s0_ * 8]);
      gl_lds16(Bb + (size_t)row0 * K + k0 + kq0, &Bs[bb ^ 1][s0_ * 8]);
      gl_lds16(Ab + (size_t)row1 * K + k0 + kq1, &As[bb ^ 1][s1_ * 8]);
      gl_lds16(Bb + (size_t)row1 * K + k0 + kq1, &Bs[bb ^ 1][s1_ * 8]);
    }
    short8 af[4], bf[4];
#pragma unroll
    for (int i = 0; i < 4; ++i) {
      af[i] = *(const short8*)(&As[bb][(mq * 64 + i * 16 + lm) * 32 + q * 8]);
      bf[i] = *(const short8*)(&Bs[bb][(nq * 64 + i * 16 + lm) * 32 + q * 8]);
    }
#pragma unroll
    for (int i = 0; i < 4; ++i)
#pragma unroll
      for (int j = 0; j < 4; ++j)
        acc[i][j] = __builtin_amdgcn_mfma_f32_16x16x32_bf16(af[i], bf[j], acc[i][j], 0, 0, 0);
    __syncthreads();  // next iter's buffer writes are fenced by this barrier
  }

#pragma unroll
  for (int i = 0; i < 4; ++i)
#pragma unroll
    for (int j = 0; j < 4; ++j)
#pragma unroll
      for (int r = 0; r < 4; ++r) {
        int m = m0 + mq * 64 + i * 16 + q * 4 + r;
        int n = n0 + nq * 64 + j * 16 + lm;
        float v = acc[i][j][r];
        if constexpr (MODE == 0) {
          ((float*)Out0)[(size_t)m * N + n] = v;
        } else {
          int b = m >> 11, t = m & (T_SEQ - 1);
          if (n < 2048) {
            int h = n >> 7, d = n & (HD - 1);
            ((u16*)Out0)[(((size_t)(b * NHEAD + h)) * T_SEQ + t) * HD + d] = f2bf(v * QSCALE);
          } else if (n < 2560) {
            int nn = n - 2048, h = nn >> 7, d = nn & (HD - 1);
            OutK[(((size_t)(b * NKV + h)) * T_SEQ + t) * HD + d] = f2bf(v);
          } else {
            int nn = n - 2560, h = nn >> 7, d = nn & (HD - 1);
            OutV[(((size_t)(b * NKV + h)) * HD + d) * T_SEQ + t] = f2bf(v);
          }
        }
      }
}

// ---------------- flash attention v4: LDS-staged K/V ----------------
// S^T: mfma(kb, qa) -> C[s][qrow].  O^T: mfma(vb, pa) -> C[d][qrow]: alpha/l_i
// rescale is pure per-lane. K/V tiles staged to LDS by global_load_lds DMA,
// double-buffered, shared by all 4 waves (4x less VMEM, zero VGPR cost).
// Slot XOR-swizzle (K: ^s&15, V: ^d&7) spreads b128 reads evenly over banks.
// 512 blocks (2/CU); pair {31-p, p} -> uniform 33 steps. One barrier/step.
// Q:[B,NH,T,HD] (pre-scaled QSCALE)  K:[B,NKV,T,HD]  V:[B,NKV,HD,T]
#define PSTRIDE 72
__global__ __launch_bounds__(256, 2) void attnk(
    const u16* __restrict__ Q, const u16* __restrict__ Kh,
    const u16* __restrict__ Vt, u16* __restrict__ Oa) {
  __shared__ __align__(16) u16 Ks[2][64 * 128];   // [s][d], slot^ (s&15)
  __shared__ __align__(16) u16 Vs[2][128 * 64];   // [d][s], slot^ (d&7)
  __shared__ __align__(16) u16 Pl[4][16 * PSTRIDE];
  const int tid = threadIdx.x;
  const int w = tid >> 6, l = tid & 63, lm = l & 15, q = l >> 4;
  const int bh = blockIdx.y, b = bh >> 4, h = bh & 15, kvh = h >> 2;
  const u16* Kb = Kh + ((size_t)(b * NKV + kvh)) * T_SEQ * HD;
  const u16* Vb = Vt + ((size_t)(b * NKV + kvh)) * HD * T_SEQ;
  u16* Pw = Pl[w];
  const int p = blockIdx.x;  // 0..15

  // staging decomposition (per thread, 4+4 DMA instrs per tile)
  const int r16 = tid >> 4, c16 = tid & 15;  // K: row group, phys slot
  const int r8  = tid >> 3, c8  = tid & 7;   // V: row group, phys slot

#pragma unroll 1
  for (int half = 0; half < 2; ++half) {
    const int tile = half ? p : (31 - p);  // heavy tile first
    const int tbase = tile * 64 + w * 16;
    const u16* Qb = Q + (((size_t)(b * NHEAD + h)) * T_SEQ + tbase) * HD;

    short8 qa[4];
#pragma unroll
    for (int ks = 0; ks < 4; ++ks)
      qa[ks] = *(const short8*)(Qb + (size_t)lm * HD + ks * 32 + q * 8);

    float m_i = NEGBIG, l_i = 0.f;
    f32x4 oacc[8] = {};
    const int nst = tile + 1;

    // prologue: stage step 0 into buffer 0
    {
#pragma unroll
      for (int j = 0; j < 4; ++j) {
        int s = j * 16 + r16, g = c16 ^ (s & 15);
        gl_lds16(Kb + (size_t)s * HD + g * 8, &Ks[0][s * 128 + c16 * 8]);
      }
#pragma unroll
      for (int j = 0; j < 4; ++j) {
        int d = j * 32 + r8, g = c8 ^ (d & 7);
        gl_lds16(Vb + (size_t)d * T_SEQ + g * 8, &Vs[0][d * 64 + c8 * 8]);
      }
    }
    __syncthreads();

    for (int st = 0; st < nst; ++st) {
      const int bb = st & 1;
      // prefetch next tile into other buffer (overlaps with this step's compute)
      if (st + 1 < nst) {
        const int s0n = (st + 1) * 64;
#pragma unroll
        for (int j = 0; j < 4; ++j) {
          int s = j * 16 + r16, g = c16 ^ (s & 15);
          gl_lds16(Kb + (size_t)(s0n + s) * HD + g * 8, &Ks[bb ^ 1][s * 128 + c16 * 8]);
        }
#pragma unroll
        for (int j = 0; j < 4; ++j) {
          int d = j * 32 + r8, g = c8 ^ (d & 7);
          gl_lds16(Vb + (size_t)d * T_SEQ + s0n + g * 8, &Vs[bb ^ 1][d * 64 + c8 * 8]);
        }
      }

      // QK^T from LDS K-tile
      f32x4 sacc[4] = {};
#pragma unroll
      for (int ks = 0; ks < 4; ++ks)
#pragma unroll
        for (int nt = 0; nt < 4; ++nt) {
          short8 kb = *(const short8*)(&Ks[bb][(nt * 16 + lm) * 128 + ((ks * 4 + q) ^ lm) * 8]);
          sacc[nt] = __builtin_amdgcn_mfma_f32_16x16x32_bf16(kb, qa[ks], sacc[nt], 0, 0, 0);
        }

      const bool diag = (st == nst - 1);
      const int s0 = st * 64;
      float mx = m_i;
      float pe[4][4];
#pragma unroll
      for (int nt = 0; nt < 4; ++nt)
#pragma unroll
        for (int j = 0; j < 4; ++j) {
          float v = sacc[nt][j];
          if (diag) {
            int s_abs = s0 + nt * 16 + q * 4 + j;
            if (s_abs > tbase + lm) v = NEGBIG;
          }
          pe[nt][j] = v;
          mx = fmaxf(mx, v);
        }
      mx = fmaxf(mx, __shfl_xor(mx, 16, 64));
      mx = fmaxf(mx, __shfl_xor(mx, 32, 64));
      float alpha = exp2f(m_i - mx);
      float sum = 0.f;
#pragma unroll
      for (int nt = 0; nt < 4; ++nt) {
        u16 pk[4];
#pragma unroll
        for (int j = 0; j < 4; ++j) {
          float e = exp2f(pe[nt][j] - mx);
          sum += e;
          pk[j] = f2bf(e);
        }
        *(u64*)(Pw + lm * PSTRIDE + nt * 16 + q * 4) =
            (u64)pk[0] | ((u64)pk[1] << 16) | ((u64)pk[2] << 32) | ((u64)pk[3] << 48);
      }
      sum += __shfl_xor(sum, 16, 64);
      sum += __shfl_xor(sum, 32, 64);
      m_i = mx;
      l_i = l_i * alpha + sum;

      // rescale O^T by alpha: per-lane (col = qrow = lm) — no cross-lane ops
#pragma unroll
      for (int dt = 0; dt < 8; ++dt)
#pragma unroll
        for (int j = 0; j < 4; ++j) oacc[dt][j] *= alpha;

      // pin compile-time order: P LDS-writes precede PV LDS-reads
      asm volatile("" ::: "memory");

      // PV from LDS V-tile: O^T += V^T · P~
#pragma unroll
      for (int ks = 0; ks < 2; ++ks) {
        short8 pa = *(const short8*)(Pw + lm * PSTRIDE + ks * 32 + q * 8);
#pragma unroll
        for (int dt = 0; dt < 8; ++dt) {
          short8 vb = *(const short8*)(
              &Vs[bb][(dt * 16 + lm) * 64 + ((ks * 4 + q) ^ (lm & 7)) * 8]);
          oacc[dt] = __builtin_amdgcn_mfma_f32_16x16x32_bf16(vb, pa, oacc[dt], 0, 0, 0);
        }
      }
      __syncthreads();  // buffers swap-safe; also drains next-tile DMA
    }

    // epilogue: O^T[d][qrow]: row d = dt*16 + q*4 + j, col qrow = lm (per-lane l_i)
    float inv = 1.0f / l_i;
    int t = tbase + lm;
#pragma unroll
    for (int dt = 0; dt < 8; ++dt) {
      u16 ok[4];
#pragma unroll
      for (int j = 0; j < 4; ++j) ok[j] = f2bf(oacc[dt][j] * inv);
      *(u64*)(Oa + ((size_t)(b * T_SEQ + t)) * (NHEAD * HD) + h * HD + dt * 16 + q * 4) =
          (u64)ok[0] | ((u64)ok[1] << 16) | ((u64)ok[2] << 32) | ((u64)ok[3] << 48);
    }
  }
}

extern "C" void kernel_launch(void* const* d_in, const int* in_sizes, int n_in,
                              void* d_out, int out_size, void* d_ws, size_t ws_size,
                              hipStream_t stream) {
  const float* x  = (const float*)d_in[0];
  const float* wq = (const float*)d_in[1];
  const float* wk = (const float*)d_in[2];
  const float* wv = (const float*)d_in[3];
  const float* wo = (const float*)d_in[4];
  float* out = (float*)d_out;

  u16* ws  = (u16*)d_ws;
  u16* xb  = ws;                      // 8M elems  (x bf16)  [later: attn out]
  u16* wqb = xb  + (8u << 20);        // 4M   } contiguous
  u16* wkb = wqb + (4u << 20);        // 1M   }  -> fused QKV weight [3072,2048]
  u16* wvb = wkb + (1u << 20);        // 1M   }
  u16* wob = wvb + (1u << 20);        // 4M
  u16* Qb  = wob + (4u << 20);        // 8M
  u16* Kb  = Qb  + (8u << 20);        // 2M
  u16* Vtb = Kb  + (2u << 20);        // 2M
  u16* Ab  = xb;                      // alias: 8M  (total 30M elems = 60 MB)

  // 1. fused cast (dst = ws[0 .. 18M) contiguous in exactly this order)
  castk_all<<<18432, 256, 0, stream>>>(x, wq, wk, wv, wo, ws);

  // 2. fused QKV projection: [4096,2048] @ [3072,2048]^T, 768 blocks = 3/CU
  gemm_bt<3><<<dim3(24, 32), 256, 0, stream>>>(xb, wqb, Qb, Kb, Vtb, 4096, 3072, 2048);

  // 3. fused RoPE on Q (65536 rows) and K (16384 rows)
  ropek_all<<<20480, 256, 0, stream>>>(Qb, Kb);

  // 4. attention: grid (16 tile-pairs, B*NHEAD = 32) = 512 blocks, 2/CU
  attnk<<<dim3(16, 32), 256, 0, stream>>>(Qb, Kb, Vtb, Ab);

  // 5. output projection -> fp32 d_out
  gemm_bt<0><<<dim3(16, 32), 256, 0, stream>>>(Ab, wob, out, nullptr, nullptr, 4096, 2048, 2048);
}

// Round 7
// 299.189 us; speedup vs baseline: 1.8074x; 1.0262x over previous
//
#include <hip/hip_runtime.h>
#include <cstdint>
#include <cstddef>

typedef unsigned short u16;
typedef unsigned u32;
typedef unsigned long long u64;
typedef __attribute__((ext_vector_type(8))) short short8;
typedef __attribute__((ext_vector_type(4))) float f32x4;

#define T_SEQ 2048
#define DM    2048
#define NHEAD 16
#define NKV   4
#define HD    128
#define NEGBIG (-3.0e38f)
// 1/sqrt(128) * log2(e): softmax runs in exp2 domain
#define QSCALE 0.1275525165017459f
// -log2(1e6)/64 for inv_freq = 2^(d * L2IF)
#define L2IF (-0.31143258583318043f)

__device__ __forceinline__ u16 f2bf(float f) {
  union { float f; unsigned u; } c; c.f = f;
  return (u16)((c.u + 0x7fffu + ((c.u >> 16) & 1u)) >> 16);
}
__device__ __forceinline__ float bf2f(u16 b) {
  union { float f; unsigned u; } c; c.u = ((unsigned)b) << 16;
  return c.f;
}
__device__ __forceinline__ void gl_lds16(const u16* g, u16* l) {
  __builtin_amdgcn_global_load_lds(
      (const __attribute__((address_space(1))) void*)g,
      (__attribute__((address_space(3))) void*)l, 16, 0, 0);
}

// ---------------- fused cast fp32 -> bf16 (all 5 tensors, dst contiguous) ---
__global__ void castk_all(const float* __restrict__ x, const float* __restrict__ wq,
                          const float* __restrict__ wk, const float* __restrict__ wv,
                          const float* __restrict__ wo, u16* __restrict__ dst) {
  long long i4 = (long long)blockIdx.x * 256 + threadIdx.x;  // unit = 4 elems
  const float* src; long long off;
  if (i4 < (2LL << 20))                    { src = x;  off = i4; }
  else if (i4 < (3LL << 20))               { src = wq; off = i4 - (2LL << 20); }
  else if (i4 < (3LL << 20) + (1 << 18))   { src = wk; off = i4 - (3LL << 20); }
  else if (i4 < (3LL << 20) + (2 << 18))   { src = wv; off = i4 - (3LL << 20) - (1 << 18); }
  else                                     { src = wo; off = i4 - (3LL << 20) - (2 << 18); }
  float4 v = *(const float4*)(src + off * 4);
  u16* d = dst + i4 * 4;
  d[0] = f2bf(v.x); d[1] = f2bf(v.y); d[2] = f2bf(v.z); d[3] = f2bf(v.w);
}

// ---------------- RoPE in-place on K only ([rows, HD] bf16) ----------------
__global__ void ropek(u16* __restrict__ buf) {
  int idx = blockIdx.x * 256 + threadIdx.x;
  int r = idx >> 6, i = idx & 63;
  int t = r & (T_SEQ - 1);
  float inv = exp2f((float)i * L2IF);
  float ang = (float)t * inv;
  float c = cosf(ang), s = sinf(ang);
  size_t base = (size_t)r * HD + i;
  float x1 = bf2f(buf[base]), x2 = bf2f(buf[base + 64]);
  buf[base]      = f2bf(x1 * c - x2 * s);
  buf[base + 64] = f2bf(x2 * c + x1 * s);
}

// ---------------- GEMM: C[M,N] = A[M,K] @ Bm[N,K]^T  (bf16 in, MFMA) -------
// K-loop: double-buffered LDS, prefetch DMA issued at top of iter, ONE
// barrier per iter (end-of-iter drain overlaps with this iter's compute).
// MODE 0: fp32 plain row-major out (Out0)
// MODE 3: fused QKV epilogue: n<2048 -> Q [B,NH,T,HD] *QSCALE;
//         n<2560 -> K [B,NKV,T,HD]; else V^T [B,NKV,HD,T]
template <int MODE>
__global__ __launch_bounds__(256) void gemm_bt(
    const u16* __restrict__ A, const u16* __restrict__ Bm,
    void* __restrict__ Out0, u16* __restrict__ OutK, u16* __restrict__ OutV,
    int M, int N, int K) {
  __shared__ __align__(16) u16 As[2][128 * 32];
  __shared__ __align__(16) u16 Bs[2][128 * 32];
  const int tid = threadIdx.x;
  const int w = tid >> 6, l = tid & 63;
  const int lm = l & 15, q = l >> 4;
  const int m0 = blockIdx.y * 128, n0 = blockIdx.x * 128;
  const int mq = w & 1, nq = w >> 1;
  const u16* Ab = A + (size_t)m0 * K;
  const u16* Bb = Bm + (size_t)n0 * K;

  // staging decomposition: slot s -> row = s>>2, k-quarter = s&3
  const int s0_ = w * 64 + l, s1_ = 256 + s0_;
  const int row0 = s0_ >> 2, kq0 = (s0_ & 3) * 8;
  const int row1 = s1_ >> 2, kq1 = (s1_ & 3) * 8;

  f32x4 acc[4][4] = {};
  const int nk = K >> 5;

  // prologue: stage k-tile 0 into buffer 0
  gl_lds16(Ab + (size_t)row0 * K + kq0, &As[0][s0_ * 8]);
  gl_lds16(Bb + (size_t)row0 * K + kq0, &Bs[0][s0_ * 8]);
  gl_lds16(Ab + (size_t)row1 * K + kq1, &As[0][s1_ * 8]);
  gl_lds16(Bb + (size_t)row1 * K + kq1, &Bs[0][s1_ * 8]);
  __syncthreads();

  for (int ki = 0; ki < nk; ++ki) {
    const int bb = ki & 1;
    if (ki + 1 < nk) {  // prefetch next k-tile into other buffer
      const int k0 = (ki + 1) << 5;
      gl_lds16(Ab + (size_t)row0 * K + k0 + kq0, &As[bb ^ 1][s0_ * 8]);
      gl_lds16(Bb + (size_t)row0 * K + k0 + kq0, &Bs[bb ^ 1][s0_ * 8]);
      gl_lds16(Ab + (size_t)row1 * K + k0 + kq1, &As[bb ^ 1][s1_ * 8]);
      gl_lds16(Bb + (size_t)row1 * K + k0 + kq1, &Bs[bb ^ 1][s1_ * 8]);
    }
    short8 af[4], bf[4];
#pragma unroll
    for (int i = 0; i < 4; ++i) {
      af[i] = *(const short8*)(&As[bb][(mq * 64 + i * 16 + lm) * 32 + q * 8]);
      bf[i] = *(const short8*)(&Bs[bb][(nq * 64 + i * 16 + lm) * 32 + q * 8]);
    }
#pragma unroll
    for (int i = 0; i < 4; ++i)
#pragma unroll
      for (int j = 0; j < 4; ++j)
        acc[i][j] = __builtin_amdgcn_mfma_f32_16x16x32_bf16(af[i], bf[j], acc[i][j], 0, 0, 0);
    __syncthreads();  // next iter's buffer writes are fenced by this barrier
  }

#pragma unroll
  for (int i = 0; i < 4; ++i)
#pragma unroll
    for (int j = 0; j < 4; ++j)
#pragma unroll
      for (int r = 0; r < 4; ++r) {
        int m = m0 + mq * 64 + i * 16 + q * 4 + r;
        int n = n0 + nq * 64 + j * 16 + lm;
        float v = acc[i][j][r];
        if constexpr (MODE == 0) {
          ((float*)Out0)[(size_t)m * N + n] = v;
        } else {
          int b = m >> 11, t = m & (T_SEQ - 1);
          if (n < 2048) {
            int h = n >> 7, d = n & (HD - 1);
            ((u16*)Out0)[(((size_t)(b * NHEAD + h)) * T_SEQ + t) * HD + d] = f2bf(v * QSCALE);
          } else if (n < 2560) {
            int nn = n - 2048, h = nn >> 7, d = nn & (HD - 1);
            OutK[(((size_t)(b * NKV + h)) * T_SEQ + t) * HD + d] = f2bf(v);
          } else {
            int nn = n - 2560, h = nn >> 7, d = nn & (HD - 1);
            OutV[(((size_t)(b * NKV + h)) * HD + d) * T_SEQ + t] = f2bf(v);
          }
        }
      }
}

// ---------------- flash attention v5 ----------------
// v4 structure (LDS-staged dbuf K/V, S^T / O^T orientation, barrier-per-step)
// + VALU trims: v_perm truncation pack for P, __any-gated alpha rescale,
// Q-RoPE fused into the Q fragment load (pairs (d,d+64) are lane-local).
// Q:[B,NH,T,HD] raw*QSCALE (RoPE applied here)  K:[B,NKV,T,HD] (RoPE'd)
// V:[B,NKV,HD,T]
#define PSTRIDE 72
__global__ __launch_bounds__(256, 2) void attnk(
    const u16* __restrict__ Q, const u16* __restrict__ Kh,
    const u16* __restrict__ Vt, u16* __restrict__ Oa) {
  __shared__ __align__(16) u16 Ks[2][64 * 128];   // [s][d], slot^ (s&15)
  __shared__ __align__(16) u16 Vs[2][128 * 64];   // [d][s], slot^ (d&7)
  __shared__ __align__(16) u16 Pl[4][16 * PSTRIDE];
  const int tid = threadIdx.x;
  const int w = tid >> 6, l = tid & 63, lm = l & 15, q = l >> 4;
  const int bh = blockIdx.y, b = bh >> 4, h = bh & 15, kvh = h >> 2;
  const u16* Kb = Kh + ((size_t)(b * NKV + kvh)) * T_SEQ * HD;
  const u16* Vb = Vt + ((size_t)(b * NKV + kvh)) * HD * T_SEQ;
  u16* Pw = Pl[w];
  const int p = blockIdx.x;  // 0..15

  // staging decomposition (per thread, 4+4 DMA instrs per tile)
  const int r16 = tid >> 4, c16 = tid & 15;  // K: row group, phys slot
  const int r8  = tid >> 3, c8  = tid & 7;   // V: row group, phys slot

#pragma unroll 1
  for (int half = 0; half < 2; ++half) {
    const int tile = half ? p : (31 - p);  // heavy tile first
    const int tbase = tile * 64 + w * 16;
    const u16* Qb = Q + (((size_t)(b * NHEAD + h)) * T_SEQ + tbase) * HD;

    short8 qa[4];
#pragma unroll
    for (int ks = 0; ks < 4; ++ks)
      qa[ks] = *(const short8*)(Qb + (size_t)lm * HD + ks * 32 + q * 8);

    // fused Q-RoPE: element e of qa[ks] is d = ks*32 + q*8 + e; pair (d, d+64)
    // lives at (qa[ks], qa[ks+2]) in the SAME lane. Once per tile (~33 steps).
    {
      const float tf = (float)(tbase + lm);
#pragma unroll
      for (int ks = 0; ks < 2; ++ks) {
        short8 lo = qa[ks], hi = qa[ks + 2];
#pragma unroll
        for (int e = 0; e < 8; ++e) {
          int d = ks * 32 + q * 8 + e;
          float ang = tf * exp2f((float)d * L2IF);
          float sn, cs;
          sincosf(ang, &sn, &cs);
          float x1 = bf2f((u16)lo[e]), x2 = bf2f((u16)hi[e]);
          lo[e] = (short)f2bf(x1 * cs - x2 * sn);
          hi[e] = (short)f2bf(x2 * cs + x1 * sn);
        }
        qa[ks] = lo; qa[ks + 2] = hi;
      }
    }

    float m_i = NEGBIG, l_i = 0.f;
    f32x4 oacc[8] = {};
    const int nst = tile + 1;

    // prologue: stage step 0 into buffer 0
    {
#pragma unroll
      for (int j = 0; j < 4; ++j) {
        int s = j * 16 + r16, g = c16 ^ (s & 15);
        gl_lds16(Kb + (size_t)s * HD + g * 8, &Ks[0][s * 128 + c16 * 8]);
      }
#pragma unroll
      for (int j = 0; j < 4; ++j) {
        int d = j * 32 + r8, g = c8 ^ (d & 7);
        gl_lds16(Vb + (size_t)d * T_SEQ + g * 8, &Vs[0][d * 64 + c8 * 8]);
      }
    }
    __syncthreads();

    for (int st = 0; st < nst; ++st) {
      const int bb = st & 1;
      // prefetch next tile into other buffer (overlaps with this step's compute)
      if (st + 1 < nst) {
        const int s0n = (st + 1) * 64;
#pragma unroll
        for (int j = 0; j < 4; ++j) {
          int s = j * 16 + r16, g = c16 ^ (s & 15);
          gl_lds16(Kb + (size_t)(s0n + s) * HD + g * 8, &Ks[bb ^ 1][s * 128 + c16 * 8]);
        }
#pragma unroll
        for (int j = 0; j < 4; ++j) {
          int d = j * 32 + r8, g = c8 ^ (d & 7);
          gl_lds16(Vb + (size_t)d * T_SEQ + s0n + g * 8, &Vs[bb ^ 1][d * 64 + c8 * 8]);
        }
      }

      // QK^T from LDS K-tile
      f32x4 sacc[4] = {};
#pragma unroll
      for (int ks = 0; ks < 4; ++ks)
#pragma unroll
        for (int nt = 0; nt < 4; ++nt) {
          short8 kb = *(const short8*)(&Ks[bb][(nt * 16 + lm) * 128 + ((ks * 4 + q) ^ lm) * 8]);
          sacc[nt] = __builtin_amdgcn_mfma_f32_16x16x32_bf16(kb, qa[ks], sacc[nt], 0, 0, 0);
        }

      const bool diag = (st == nst - 1);
      const int s0 = st * 64;
      float mx = m_i;
      float pe[4][4];
#pragma unroll
      for (int nt = 0; nt < 4; ++nt)
#pragma unroll
        for (int j = 0; j < 4; ++j) {
          float v = sacc[nt][j];
          if (diag) {
            int s_abs = s0 + nt * 16 + q * 4 + j;
            if (s_abs > tbase + lm) v = NEGBIG;
          }
          pe[nt][j] = v;
          mx = fmaxf(mx, v);
        }
      mx = fmaxf(mx, __shfl_xor(mx, 16, 64));
      mx = fmaxf(mx, __shfl_xor(mx, 32, 64));
      float alpha = exp2f(m_i - mx);
      float sum = 0.f;
#pragma unroll
      for (int nt = 0; nt < 4; ++nt) {
        float e0 = exp2f(pe[nt][0] - mx), e1 = exp2f(pe[nt][1] - mx);
        float e2 = exp2f(pe[nt][2] - mx), e3 = exp2f(pe[nt][3] - mx);
        sum += (e0 + e1) + (e2 + e3);
        // truncation-pack two fp32 -> u32 of bf16 pair (1 v_perm each)
        u32 lo32 = __builtin_amdgcn_perm(__float_as_uint(e1), __float_as_uint(e0), 0x07060302u);
        u32 hi32 = __builtin_amdgcn_perm(__float_as_uint(e3), __float_as_uint(e2), 0x07060302u);
        *(u64*)(Pw + lm * PSTRIDE + nt * 16 + q * 4) = ((u64)hi32 << 32) | lo32;
      }
      sum += __shfl_xor(sum, 16, 64);
      sum += __shfl_xor(sum, 32, 64);
      bool bump = (mx > m_i);
      m_i = mx;
      l_i = l_i * alpha + sum;

      // rescale O^T by alpha only if some lane's max moved (wave-uniform skip)
      if (__any(bump)) {
#pragma unroll
        for (int dt = 0; dt < 8; ++dt)
#pragma unroll
          for (int j = 0; j < 4; ++j) oacc[dt][j] *= alpha;
      }

      // pin compile-time order: P LDS-writes precede PV LDS-reads
      asm volatile("" ::: "memory");

      // PV from LDS V-tile: O^T += V^T · P~
#pragma unroll
      for (int ks = 0; ks < 2; ++ks) {
        short8 pa = *(const short8*)(Pw + lm * PSTRIDE + ks * 32 + q * 8);
#pragma unroll
        for (int dt = 0; dt < 8; ++dt) {
          short8 vb = *(const short8*)(
              &Vs[bb][(dt * 16 + lm) * 64 + ((ks * 4 + q) ^ (lm & 7)) * 8]);
          oacc[dt] = __builtin_amdgcn_mfma_f32_16x16x32_bf16(vb, pa, oacc[dt], 0, 0, 0);
        }
      }
      __syncthreads();  // buffers swap-safe; also drains next-tile DMA
    }

    // epilogue: O^T[d][qrow]: row d = dt*16 + q*4 + j, col qrow = lm (per-lane l_i)
    float inv = 1.0f / l_i;
    int t = tbase + lm;
#pragma unroll
    for (int dt = 0; dt < 8; ++dt) {
      u16 ok[4];
#pragma unroll
      for (int j = 0; j < 4; ++j) ok[j] = f2bf(oacc[dt][j] * inv);
      *(u64*)(Oa + ((size_t)(b * T_SEQ + t)) * (NHEAD * HD) + h * HD + dt * 16 + q * 4) =
          (u64)ok[0] | ((u64)ok[1] << 16) | ((u64)ok[2] << 32) | ((u64)ok[3] << 48);
    }
  }
}

extern "C" void kernel_launch(void* const* d_in, const int* in_sizes, int n_in,
                              void* d_out, int out_size, void* d_ws, size_t ws_size,
                              hipStream_t stream) {
  const float* x  = (const float*)d_in[0];
  const float* wq = (const float*)d_in[1];
  const float* wk = (const float*)d_in[2];
  const float* wv = (const float*)d_in[3];
  const float* wo = (const float*)d_in[4];
  float* out = (float*)d_out;

  u16* ws  = (u16*)d_ws;
  u16* xb  = ws;                      // 8M elems  (x bf16)  [later: attn out]
  u16* wqb = xb  + (8u << 20);        // 4M   } contiguous
  u16* wkb = wqb + (4u << 20);        // 1M   }  -> fused QKV weight [3072,2048]
  u16* wvb = wkb + (1u << 20);        // 1M   }
  u16* wob = wvb + (1u << 20);        // 4M
  u16* Qb  = wob + (4u << 20);        // 8M
  u16* Kb  = Qb  + (8u << 20);        // 2M
  u16* Vtb = Kb  + (2u << 20);        // 2M
  u16* Ab  = xb;                      // alias: 8M  (total 30M elems = 60 MB)

  // 1. fused cast (dst = ws[0 .. 18M) contiguous in exactly this order)
  castk_all<<<18432, 256, 0, stream>>>(x, wq, wk, wv, wo, ws);

  // 2. fused QKV projection: [4096,2048] @ [3072,2048]^T, 768 blocks = 3/CU
  gemm_bt<3><<<dim3(24, 32), 256, 0, stream>>>(xb, wqb, Qb, Kb, Vtb, 4096, 3072, 2048);

  // 3. RoPE on K only (Q-RoPE is fused into attnk's fragment load)
  ropek<<<4096, 256, 0, stream>>>(Kb);

  // 4. attention: grid (16 tile-pairs, B*NHEAD = 32) = 512 blocks, 2/CU
  attnk<<<dim3(16, 32), 256, 0, stream>>>(Qb, Kb, Vtb, Ab);

  // 5. output projection -> fp32 d_out
  gemm_bt<0><<<dim3(16, 32), 256, 0, stream>>>(Ab, wob, out, nullptr, nullptr, 4096, 2048, 2048);
}